// Round 3
// baseline (70.140 us; speedup 1.0000x reference)
//
#include <hip/hip_runtime.h>

// out = (idx even) ? sin(x) : cos(x), 4096x8192 f32/i32.
// Memory-bound streaming. Round 3: unroll 8 (16 loads in flight/thread) to
// squeeze out residual latency stalls; NT stores kept (harmless).
// cos(x) = sin(x + 0.25 revolutions) -> single v_sin_f32 per element.

typedef float vfloat4 __attribute__((ext_vector_type(4)));
typedef int   vint4   __attribute__((ext_vector_type(4)));

__device__ __forceinline__ float sincos_sel(float x, int odd) {
    const float INV2PI = 0.15915493667125702f;  // 1/(2*pi)
    float t = __builtin_fmaf(x, INV2PI, odd ? 0.25f : 0.0f);
    return __builtin_amdgcn_sinf(t);            // v_sin_f32: sin(t * 2*pi)
}

#define UNROLL 8

__global__ void __launch_bounds__(256) sincos_sel_kernel(
    const vfloat4* __restrict__ x,
    const vint4*  __restrict__ idx,
    vfloat4* __restrict__ out,
    int n4)
{
    const int tid    = blockIdx.x * blockDim.x + threadIdx.x;
    const int stride = gridDim.x * blockDim.x;

    int i = tid;
    // main: 8 independent vec4 chunks per iteration -> 16 loads in flight
    for (; i + (UNROLL - 1) * stride < n4; i += UNROLL * stride) {
        vfloat4 xv[UNROLL];
        vint4   dv[UNROLL];
        #pragma unroll
        for (int u = 0; u < UNROLL; ++u) xv[u] = x[i + u * stride];
        #pragma unroll
        for (int u = 0; u < UNROLL; ++u) dv[u] = idx[i + u * stride];

        #pragma unroll
        for (int u = 0; u < UNROLL; ++u) {
            vfloat4 o;
            #pragma unroll
            for (int j = 0; j < 4; ++j) o[j] = sincos_sel(xv[u][j], dv[u][j] & 1);
            __builtin_nontemporal_store(o, &out[i + u * stride]);
        }
    }
    // tail
    for (; i < n4; i += stride) {
        vfloat4 xv = x[i];
        vint4   dv = idx[i];
        vfloat4 o;
        #pragma unroll
        for (int j = 0; j < 4; ++j) o[j] = sincos_sel(xv[j], dv[j] & 1);
        __builtin_nontemporal_store(o, &out[i]);
    }
}

extern "C" void kernel_launch(void* const* d_in, const int* in_sizes, int n_in,
                              void* d_out, int out_size, void* d_ws, size_t ws_size,
                              hipStream_t stream)
{
    const vfloat4* x   = (const vfloat4*)d_in[0];
    const vint4*   idx = (const vint4*)d_in[1];
    vfloat4*       out = (vfloat4*)d_out;

    const int n  = in_sizes[0];   // 33,554,432
    const int n4 = n >> 2;        // 8,388,608 vec4 chunks

    const int block = 256;
    const int grid  = 2048;       // 8 blocks/CU x 256 CUs; 16 chunks/thread (2 unrolled iters)

    sincos_sel_kernel<<<grid, block, 0, stream>>>(x, idx, out, n4);
}

// Round 4
// 64.705 us; speedup vs baseline: 1.0840x; 1.0840x over previous
//
#include <hip/hip_runtime.h>

// out = (idx even) ? sin(x) : cos(x), 4096x8192 f32/i32.
// Round 4: round-2 structure (UNROLL=4, 66.2 us) + system-scope non-temporal
// stores ("sc0 nt sc1") to keep the 128 MiB output stream from allocating in
// the 256 MiB Infinity Cache, so the 256 MiB input set can stay L3-resident
// across graph replays. cos(x) = sin(x + 0.25 rev) -> one v_sin_f32/element.

typedef float vfloat4 __attribute__((ext_vector_type(4)));
typedef int   vint4   __attribute__((ext_vector_type(4)));

__device__ __forceinline__ float sincos_sel(float x, int odd) {
    const float INV2PI = 0.15915493667125702f;  // 1/(2*pi)
    float t = __builtin_fmaf(x, INV2PI, odd ? 0.25f : 0.0f);
    return __builtin_amdgcn_sinf(t);            // v_sin_f32: sin(t * 2*pi)
}

// System-scope non-temporal 16B store: bypass/write-around L2 and MALL.
__device__ __forceinline__ void store_wt(vfloat4* addr, vfloat4 v) {
    asm volatile("global_store_dwordx4 %0, %1, off sc0 nt sc1"
                 :: "v"(addr), "v"(v) : "memory");
}

__global__ void __launch_bounds__(256) sincos_sel_kernel(
    const vfloat4* __restrict__ x,
    const vint4*  __restrict__ idx,
    vfloat4* __restrict__ out,
    int n4)
{
    const int tid    = blockIdx.x * blockDim.x + threadIdx.x;
    const int stride = gridDim.x * blockDim.x;

    int i = tid;
    // main: 4 independent vec4 chunks per iteration -> 8 loads in flight
    for (; i + 3 * stride < n4; i += 4 * stride) {
        vfloat4 x0 = x[i];
        vfloat4 x1 = x[i +     stride];
        vfloat4 x2 = x[i + 2 * stride];
        vfloat4 x3 = x[i + 3 * stride];
        vint4   d0 = idx[i];
        vint4   d1 = idx[i +     stride];
        vint4   d2 = idx[i + 2 * stride];
        vint4   d3 = idx[i + 3 * stride];

        vfloat4 o0, o1, o2, o3;
        #pragma unroll
        for (int j = 0; j < 4; ++j) {
            o0[j] = sincos_sel(x0[j], d0[j] & 1);
            o1[j] = sincos_sel(x1[j], d1[j] & 1);
            o2[j] = sincos_sel(x2[j], d2[j] & 1);
            o3[j] = sincos_sel(x3[j], d3[j] & 1);
        }
        store_wt(&out[i],              o0);
        store_wt(&out[i +     stride], o1);
        store_wt(&out[i + 2 * stride], o2);
        store_wt(&out[i + 3 * stride], o3);
    }
    // tail (not taken for n4 = 8M with grid 2048x256, kept for safety)
    for (; i < n4; i += stride) {
        vfloat4 xv = x[i];
        vint4   dv = idx[i];
        vfloat4 o;
        #pragma unroll
        for (int j = 0; j < 4; ++j) o[j] = sincos_sel(xv[j], dv[j] & 1);
        store_wt(&out[i], o);
    }
}

extern "C" void kernel_launch(void* const* d_in, const int* in_sizes, int n_in,
                              void* d_out, int out_size, void* d_ws, size_t ws_size,
                              hipStream_t stream)
{
    const vfloat4* x   = (const vfloat4*)d_in[0];
    const vint4*   idx = (const vint4*)d_in[1];
    vfloat4*       out = (vfloat4*)d_out;

    const int n  = in_sizes[0];   // 33,554,432
    const int n4 = n >> 2;        // 8,388,608 vec4 chunks

    const int block = 256;
    const int grid  = 2048;       // 8 blocks/CU x 256 CUs; 16 chunks/thread

    sincos_sel_kernel<<<grid, block, 0, stream>>>(x, idx, out, n4);
}